// Round 4
// baseline (353.514 us; speedup 1.0000x reference)
//
#include <hip/hip_runtime.h>
#include <hip/hip_bf16.h>
#include <stdint.h>

// LSH: project -> sign-bit-pack -> Hamming via xor+popcount -> cos
// packed codes in d_ws: [12288 rows][16 u64]; word w holds bits w*64..+63,
// bit b of word = sign(dot(emb[row], r[w*64+b])). Identical bit order for
// u and v, so xor-popcount Hamming is exact.

#define NBITS   1024
#define NROWS1  4096
#define NROWS2  8192

// ---------------------------------------------------------------------------
// Kernel 1: projection + sign + pack. ZERO LDS, zero barriers.
// Grid (48 rowBlks, 16 words), block 256. Thread = 1 emb row x 64 bits
// (one u64 word). K=128 in 4 chunks of 32:
//   - emb row chunk: 8 float4 in VGPRs (contiguous 128 B per lane).
//   - r values are wave-uniform (bit index is blockIdx/loop-derived):
//     readfirstlane-forced scalar loads -> s_load_dwordx4 into SGPRs,
//     double-buffered 2 bits ahead (ra/rb). FMA = v_fma(vgpr, sgpr, vgpr).
//   - acc[64] f32: 64-deep ILP, no cross-lane ops, no ballot.
// VALU floor: 12288*1024*128 lane-FMA = 1.61G / 78.6T = 20.5 us.
// ---------------------------------------------------------------------------
__global__ __launch_bounds__(256, 4) void lsh_project_pack(
    const float4* __restrict__ emb1,
    const float4* __restrict__ emb2,
    const float4* __restrict__ r4,
    unsigned long long* __restrict__ packed)
{
  const int t      = threadIdx.x;
  const int rowBlk = blockIdx.x;     // 0..47  (256 rows each)
  const int word   = blockIdx.y;     // 0..15  (64 bits each)

  const int rowStart = rowBlk * 256;
  const bool side1   = rowStart < NROWS1;           // uniform per block
  const float4* __restrict__ eb4 = side1 ? emb1 : emb2;
  const int rowLoc = (side1 ? rowStart : rowStart - NROWS1) + t;
  const int bit0   = word * 64;

  float acc[64];
#pragma unroll
  for (int b = 0; b < 64; ++b) acc[b] = 0.0f;

  for (int ch = 0; ch < 4; ++ch) {
    // own emb row chunk -> VGPRs (two full 64B lines per lane, no overfetch)
    float4 E[8];
#pragma unroll
    for (int c = 0; c < 8; ++c)
      E[c] = eb4[(size_t)rowLoc * 32 + ch * 8 + c];

    // r scalar double-buffer: ra = bit b, rb = bit b+1
    float4 ra[8], rb[8];
    {
      const int s0 = __builtin_amdgcn_readfirstlane(bit0 * 32 + ch * 8);
#pragma unroll
      for (int c = 0; c < 8; ++c) ra[c] = r4[s0 + c];
    }

#pragma unroll
    for (int b = 0; b < 64; b += 2) {
      {
        const int s1 =
            __builtin_amdgcn_readfirstlane((bit0 + b + 1) * 32 + ch * 8);
#pragma unroll
        for (int c = 0; c < 8; ++c) rb[c] = r4[s1 + c];
      }
#pragma unroll
      for (int c = 0; c < 8; ++c) {
        acc[b] = fmaf(E[c].x, ra[c].x, acc[b]);
        acc[b] = fmaf(E[c].y, ra[c].y, acc[b]);
        acc[b] = fmaf(E[c].z, ra[c].z, acc[b]);
        acc[b] = fmaf(E[c].w, ra[c].w, acc[b]);
      }
      if (b + 2 < 64) {
        const int s2 =
            __builtin_amdgcn_readfirstlane((bit0 + b + 2) * 32 + ch * 8);
#pragma unroll
        for (int c = 0; c < 8; ++c) ra[c] = r4[s2 + c];
      }
#pragma unroll
      for (int c = 0; c < 8; ++c) {
        acc[b + 1] = fmaf(E[c].x, rb[c].x, acc[b + 1]);
        acc[b + 1] = fmaf(E[c].y, rb[c].y, acc[b + 1]);
        acc[b + 1] = fmaf(E[c].z, rb[c].z, acc[b + 1]);
        acc[b + 1] = fmaf(E[c].w, rb[c].w, acc[b + 1]);
      }
    }
  }

  // pack per-lane: bit b of the word = (acc[b] > 0)
  unsigned int w0 = 0, w1 = 0;
#pragma unroll
  for (int b = 0; b < 32; ++b) w0 |= (acc[b] > 0.0f) ? (1u << b) : 0u;
#pragma unroll
  for (int b = 0; b < 32; ++b) w1 |= (acc[32 + b] > 0.0f) ? (1u << b) : 0u;

  const int grow = rowStart + t;
  uint2 wv; wv.x = w0; wv.y = w1;              // little-endian u64
  *(uint2*)&packed[(size_t)grow * 16 + word] = wv;
}

// ---------------------------------------------------------------------------
// Kernel 2: Hamming (xor + GUARANTEED-fused popcount-accumulate) + cos.
// Same verified structure as previous round (88.5 us, VALU 82%); the only
// change is inline-asm v_bcnt_u32_b32 with the accumulator in src1, which
// removes the separate v_add chain the compiler was emitting (~2k instrs
// per thread).
// Grid (32 n-blocks, 64 m-blocks), block 256 (4 waves).
// Block tile: 64 rows x 256 cols. Thread: 8 rows x 8 cols (2 DS reads/output).
// ---------------------------------------------------------------------------
__device__ __forceinline__ void bcnt_acc(unsigned int& h, unsigned int x) {
  // h = popcount(x) + h   (v_bcnt_u32_b32 D, S0, S1 : D = bcnt(S0) + S1)
  asm("v_bcnt_u32_b32 %0, %1, %0" : "+v"(h) : "v"(x));
}

__global__ __launch_bounds__(256, 3) void lsh_hamming_cos(
    const uint4* __restrict__ up,    // [4096][8]
    const uint4* __restrict__ vp,    // [8192][8]
    const float* __restrict__ pi_in,
    float* __restrict__ out)         // [4096][8192]
{
  __shared__ uint4 u_lds[64 * 8];    // 8 KB, linear
  __shared__ uint4 v_lds[256 * 8];   // 32 KB, swizzled

  const int t  = threadIdx.x;
  const int w  = t >> 6;
  const int l  = t & 63;
  const int n0 = blockIdx.x * 256;
  const int m0 = blockIdx.y * 64;

  // stage U tile (linear, coalesced)
#pragma unroll
  for (int i = 0; i < 2; ++i)
    u_lds[t + i * 256] = up[(size_t)m0 * 8 + t + i * 256];

  // stage V tile (swizzle uint4 slot: w4 -> w4 ^ ((col>>2)&7))
#pragma unroll
  for (int i = 0; i < 8; ++i) {
    const int idx = t + i * 256;
    const int col = idx >> 3;
    const int w4  = idx & 7;
    v_lds[col * 8 + (w4 ^ ((col >> 2) & 7))] = vp[(size_t)n0 * 8 + idx];
  }
  __syncthreads();

  unsigned int h[8][8];
#pragma unroll
  for (int r = 0; r < 8; ++r)
#pragma unroll
    for (int j = 0; j < 8; ++j) h[r][j] = 0u;

  const int key  = l & 7;
  const int row0 = w * 16 + (l >> 5) * 8;   // thread's first row (block-local)
  const int c0   = (l & 31) * 4;            // thread's first col (block-local)

#pragma unroll
  for (int kk = 0; kk < 8; ++kk) {          // one uint4 (128 bits) per step
    uint4 U[8];
#pragma unroll
    for (int r = 0; r < 8; ++r)
      U[r] = u_lds[(row0 + r) * 8 + kk];    // 2-address broadcast: free
    const int slot = kk ^ key;
#pragma unroll
    for (int half = 0; half < 2; ++half) {
#pragma unroll
      for (int j = 0; j < 4; ++j) {
        const uint4 V = v_lds[(c0 + half * 128 + j) * 8 + slot];
#pragma unroll
        for (int r = 0; r < 8; ++r) {
          unsigned int& s = h[r][half * 4 + j];
          bcnt_acc(s, U[r].x ^ V.x);        // exactly 2 VALU per word
          bcnt_acc(s, U[r].y ^ V.y);
          bcnt_acc(s, U[r].z ^ V.z);
          bcnt_acc(s, U[r].w ^ V.w);
        }
      }
    }
  }

  const float scale = pi_in[0] * (1.0f / (float)NBITS);

#pragma unroll
  for (int r = 0; r < 8; ++r) {
    const size_t row = (size_t)(m0 + row0 + r);
#pragma unroll
    for (int half = 0; half < 2; ++half) {
      float4 o;
      o.x = __cosf(scale * (float)h[r][half * 4 + 0]);
      o.y = __cosf(scale * (float)h[r][half * 4 + 1]);
      o.z = __cosf(scale * (float)h[r][half * 4 + 2]);
      o.w = __cosf(scale * (float)h[r][half * 4 + 3]);
      *(float4*)(out + row * NROWS2 + n0 + c0 + half * 128) = o;
    }
  }
}

// ---------------------------------------------------------------------------
extern "C" void kernel_launch(void* const* d_in, const int* in_sizes, int n_in,
                              void* d_out, int out_size, void* d_ws, size_t ws_size,
                              hipStream_t stream) {
  const float* emb1 = (const float*)d_in[0];   // [4096][128]
  const float* emb2 = (const float*)d_in[1];   // [8192][128]
  const float* r    = (const float*)d_in[2];   // [1024][128]
  const float* pi   = (const float*)d_in[3];   // [1]

  unsigned long long* packed = (unsigned long long*)d_ws;  // [12288][16]

  dim3 g1(48, 16), b1(256);
  lsh_project_pack<<<g1, b1, 0, stream>>>(
      (const float4*)emb1, (const float4*)emb2, (const float4*)r, packed);

  dim3 g2(32, 64), b2(256);
  lsh_hamming_cos<<<g2, b2, 0, stream>>>(
      (const uint4*)packed,
      (const uint4*)(packed + (size_t)NROWS1 * 16),
      pi, (float*)d_out);
}

// Round 5
// 321.492 us; speedup vs baseline: 1.0996x; 1.0996x over previous
//
#include <hip/hip_runtime.h>
#include <hip/hip_bf16.h>
#include <stdint.h>

// LSH: project -> sign-bit-pack -> Hamming via xor+popcount -> cos
// packed codes in d_ws: [12288 rows][16 u64]; word w holds bits w*64..+63,
// bit b of word = sign(dot(emb[row], r[w*64+b])). Identical bit order for
// u and v, so xor-popcount Hamming is exact.

#define NBITS   1024
#define NROWS1  4096
#define NROWS2  8192

// ---------------------------------------------------------------------------
// Kernel 1: projection + sign + pack. ZERO LDS, zero barriers.
// Grid (48 rowBlks, 16 words), block 256 (4 waves). Wave = 64 rows x 64 bits.
// Lane l permanently holds r[word*64+l][0..127] in VGPRs (32 float4, loaded
// once; r is 512 KB -> L2-resident). emb rows stream through the SCALAR pipe:
// the row index is wave-uniform (readfirstlane-pinned) so the 128 float
// reads become s_load_dwordx16 into SGPRs; v_fma takes the emb value from
// the SGPR slot. Every wave streams the SAME emb bytes in the same order ->
// scalar K$ / L2 stay hot (unlike round 4, where each block streamed a
// block-specific r slice and thrashed K$).
// Per row: 128 v_fma (4 independent accumulators) + ballot -> u64 word.
// VALU floor: 12288*1024*128 lane-FMA = 1.61G / 78.6T = 20.5 us.
// ---------------------------------------------------------------------------
__global__ __launch_bounds__(256, 3) void lsh_project_pack(
    const float* __restrict__ emb1,
    const float* __restrict__ emb2,
    const float4* __restrict__ r4,
    unsigned long long* __restrict__ packed)
{
  const int t = threadIdx.x;
  const int w = t >> 6;              // wave 0..3
  const int l = t & 63;              // lane = bit within word
  const int word = blockIdx.y;       // 0..15

  const int blockRow0 = blockIdx.x * 256;        // 256 rows per block
  const bool side1    = blockRow0 < NROWS1;      // uniform (blockIdx-only)
  const float* __restrict__ ebase = side1 ? emb1 : emb2;
  const int localRow0 = (side1 ? blockRow0 : blockRow0 - NROWS1) + w * 64;

  // lane-resident r row: 32 float4 = 128 VGPRs (one-time, L2-resident)
  float4 R[32];
  {
    const float4* __restrict__ rrow = r4 + (size_t)(word * 64 + l) * 32;
#pragma unroll
    for (int c = 0; c < 32; ++c) R[c] = rrow[c];
  }

  unsigned long long keep = 0ull;    // lane l keeps row (wave_row0 + l)'s word

  for (int i = 0; i < 64; ++i) {
    // wave-uniform row -> scalar loads (s_load_dwordx16), no LDS, no VMEM
    const int rowU = __builtin_amdgcn_readfirstlane(localRow0 + i);
    const float* __restrict__ p = ebase + (size_t)rowU * 128;

    float s0 = 0.0f, s1 = 0.0f, s2 = 0.0f, s3 = 0.0f;
#pragma unroll
    for (int c = 0; c < 32; ++c) {
      const float4 rv = R[c];
      s0 = fmaf(p[c * 4 + 0], rv.x, s0);   // v_fma_f32 vD, sgpr, vgpr, vD
      s1 = fmaf(p[c * 4 + 1], rv.y, s1);
      s2 = fmaf(p[c * 4 + 2], rv.z, s2);
      s3 = fmaf(p[c * 4 + 3], rv.w, s3);
    }
    const float sum = (s0 + s1) + (s2 + s3);

    const unsigned long long m = __ballot(sum > 0.0f);  // bit b = lane b
    keep = (i == l) ? m : keep;        // 2 VALU: row i's word parks in lane i
  }

  // coalesced-ish epilogue: lane l stores row (wave_row0 + l)'s word
  const int growRow = blockRow0 + w * 64 + l;
  packed[(size_t)growRow * 16 + word] = keep;
}

// ---------------------------------------------------------------------------
// Kernel 2: Hamming (xor + popcount) + cos. EXACT round-3 code (measured
// 88.5 us, VALU 82%). The inline-asm bcnt variant regressed 2x -> reverted.
// Grid (32 n-blocks, 64 m-blocks), block 256 (4 waves).
// Block tile: 64 rows x 256 cols. Thread: 8 rows x 8 cols (2 DS reads/output).
// ---------------------------------------------------------------------------
__global__ __launch_bounds__(256, 3) void lsh_hamming_cos(
    const uint4* __restrict__ up,    // [4096][8]
    const uint4* __restrict__ vp,    // [8192][8]
    const float* __restrict__ pi_in,
    float* __restrict__ out)         // [4096][8192]
{
  __shared__ uint4 u_lds[64 * 8];    // 8 KB, linear
  __shared__ uint4 v_lds[256 * 8];   // 32 KB, swizzled

  const int t  = threadIdx.x;
  const int w  = t >> 6;
  const int l  = t & 63;
  const int n0 = blockIdx.x * 256;
  const int m0 = blockIdx.y * 64;

  // stage U tile (linear, coalesced)
#pragma unroll
  for (int i = 0; i < 2; ++i)
    u_lds[t + i * 256] = up[(size_t)m0 * 8 + t + i * 256];

  // stage V tile (swizzle uint4 slot: w4 -> w4 ^ ((col>>2)&7))
#pragma unroll
  for (int i = 0; i < 8; ++i) {
    const int idx = t + i * 256;
    const int col = idx >> 3;
    const int w4  = idx & 7;
    v_lds[col * 8 + (w4 ^ ((col >> 2) & 7))] = vp[(size_t)n0 * 8 + idx];
  }
  __syncthreads();

  int h[8][8];
#pragma unroll
  for (int r = 0; r < 8; ++r)
#pragma unroll
    for (int j = 0; j < 8; ++j) h[r][j] = 0;

  const int key  = l & 7;
  const int row0 = w * 16 + (l >> 5) * 8;   // thread's first row (block-local)
  const int c0   = (l & 31) * 4;            // thread's first col (block-local)

#pragma unroll
  for (int kk = 0; kk < 8; ++kk) {          // one uint4 (128 bits) per step
    uint4 U[8];
#pragma unroll
    for (int r = 0; r < 8; ++r)
      U[r] = u_lds[(row0 + r) * 8 + kk];    // 2-address broadcast: free
    const int slot = kk ^ key;
#pragma unroll
    for (int half = 0; half < 2; ++half) {
#pragma unroll
      for (int j = 0; j < 4; ++j) {
        const uint4 V = v_lds[(c0 + half * 128 + j) * 8 + slot];
#pragma unroll
        for (int r = 0; r < 8; ++r) {
          int s = h[r][half * 4 + j];
          s += __builtin_popcount(U[r].x ^ V.x);
          s += __builtin_popcount(U[r].y ^ V.y);
          s += __builtin_popcount(U[r].z ^ V.z);
          s += __builtin_popcount(U[r].w ^ V.w);
          h[r][half * 4 + j] = s;
        }
      }
    }
  }

  const float scale = pi_in[0] * (1.0f / (float)NBITS);

#pragma unroll
  for (int r = 0; r < 8; ++r) {
    const size_t row = (size_t)(m0 + row0 + r);
#pragma unroll
    for (int half = 0; half < 2; ++half) {
      float4 o;
      o.x = __cosf(scale * (float)h[r][half * 4 + 0]);
      o.y = __cosf(scale * (float)h[r][half * 4 + 1]);
      o.z = __cosf(scale * (float)h[r][half * 4 + 2]);
      o.w = __cosf(scale * (float)h[r][half * 4 + 3]);
      *(float4*)(out + row * NROWS2 + n0 + c0 + half * 128) = o;
    }
  }
}

// ---------------------------------------------------------------------------
extern "C" void kernel_launch(void* const* d_in, const int* in_sizes, int n_in,
                              void* d_out, int out_size, void* d_ws, size_t ws_size,
                              hipStream_t stream) {
  const float* emb1 = (const float*)d_in[0];   // [4096][128]
  const float* emb2 = (const float*)d_in[1];   // [8192][128]
  const float* r    = (const float*)d_in[2];   // [1024][128]
  const float* pi   = (const float*)d_in[3];   // [1]

  unsigned long long* packed = (unsigned long long*)d_ws;  // [12288][16]

  dim3 g1(48, 16), b1(256);
  lsh_project_pack<<<g1, b1, 0, stream>>>(
      emb1, emb2, (const float4*)r, packed);

  dim3 g2(32, 64), b2(256);
  lsh_hamming_cos<<<g2, b2, 0, stream>>>(
      (const uint4*)packed,
      (const uint4*)(packed + (size_t)NROWS1 * 16),
      pi, (float*)d_out);
}

// Round 6
// 298.606 us; speedup vs baseline: 1.1839x; 1.0766x over previous
//
#include <hip/hip_runtime.h>
#include <hip/hip_bf16.h>
#include <stdint.h>

// LSH: project -> sign-bit-pack -> Hamming via xor+popcount -> cos
// packed codes in d_ws: [12288 rows][16 u64]; word w holds bits w*64..+63,
// bit b of word = sign(dot(emb[row], r[w*64+b])). Identical bit order for
// u and v, so xor-popcount Hamming is exact.

#define NBITS   1024
#define NROWS1  4096
#define NROWS2  8192

// ---------------------------------------------------------------------------
// Kernel 1: projection + sign + pack — k2's proven LDS recipe applied to f32.
// Grid (192 rowBlks, 2 bitTiles), block 256 (4 waves).
// Block tile: 64 rows x 512 bits. Wave = 16 rows (broadcast reads, like k2's
// U). Lane l owns bit-planes p*64+l (p=0..7) -> ballot yields u64 word p.
// K=128 in 4 chunks of 32 floats:
//   e_lds [64 rows][8 float4] = 8 KB, linear (wave-uniform broadcast reads).
//   r_lds [512 bits][8 float4] = 64 KB, slot-swizzled s^(bit&7) -> 8
//     consecutive lanes hit 8 distinct 16B groups (k2's exact pattern).
// Per K-float4 step: 8 swizzled b128 + 16 broadcast b128 (~176 CU-cyc)
// feed 512 v_fma (1024 SIMD-cyc): VALU-cycles > 4x LDS-cycles -> VALU-bound.
// acc[16][8] = 128 VGPR; ~2 waves/SIMD, 2 blocks/CU (72 KB LDS).
// VALU floor: 1.61G lane-FMA / 78.6T = 20.5 us.
// ---------------------------------------------------------------------------
__global__ __launch_bounds__(256, 2) void lsh_project_pack(
    const float4* __restrict__ emb1,
    const float4* __restrict__ emb2,
    const float4* __restrict__ r4,
    unsigned long long* __restrict__ packed)
{
  __shared__ float4 e_lds[64 * 8];     // [row][ks], linear
  __shared__ float4 r_lds[512 * 8];    // [bit][slot ^ (bit&7)]

  const int t = threadIdx.x;
  const int w = t >> 6;                // wave 0..3
  const int l = t & 63;
  const int rowBlk  = blockIdx.x;      // 0..191 (64 rows each)
  const int bitTile = blockIdx.y;      // 0..1   (512 bits each)

  const int blockRow0 = rowBlk * 64;
  const bool side1    = blockRow0 < NROWS1;        // uniform (blockIdx-only)
  const float4* __restrict__ eb4 = side1 ? emb1 : emb2;
  const int rowOff = side1 ? blockRow0 : blockRow0 - NROWS1;

  float acc[16][8];
#pragma unroll
  for (int rr = 0; rr < 16; ++rr)
#pragma unroll
    for (int p = 0; p < 8; ++p) acc[rr][p] = 0.0f;

  const int key = l & 7;

  for (int ch = 0; ch < 4; ++ch) {
    __syncthreads();                   // previous chunk's reads done
    // stage e chunk: 64 rows x 8 float4 -> 2 per thread (coalesced,
    // conflict-free write: 8 consecutive lanes = 8 consecutive slots)
#pragma unroll
    for (int i = 0; i < 2; ++i) {
      const int idx = t + i * 256;
      const int row = idx >> 3;
      const int ks  = idx & 7;
      e_lds[idx] = eb4[(size_t)(rowOff + row) * 32 + ch * 8 + ks];
    }
    // stage r chunk: 512 bits x 8 float4 -> 16 per thread, swizzled
#pragma unroll
    for (int i = 0; i < 16; ++i) {
      const int idx = t + i * 256;
      const int bit = idx >> 3;
      const int s   = idx & 7;
      r_lds[bit * 8 + (s ^ (bit & 7))] =
          r4[(size_t)(bitTile * 512 + bit) * 32 + ch * 8 + s];
    }
    __syncthreads();

#pragma unroll
    for (int ks = 0; ks < 8; ++ks) {
      float4 rv[8];
#pragma unroll
      for (int p = 0; p < 8; ++p)
        rv[p] = r_lds[(p * 64 + l) * 8 + (ks ^ key)];   // conflict-free
#pragma unroll
      for (int rr = 0; rr < 16; ++rr) {
        const float4 ev = e_lds[(w * 16 + rr) * 8 + ks]; // broadcast
#pragma unroll
        for (int p = 0; p < 8; ++p) {
          acc[rr][p] = fmaf(ev.x, rv[p].x, acc[rr][p]);
          acc[rr][p] = fmaf(ev.y, rv[p].y, acc[rr][p]);
          acc[rr][p] = fmaf(ev.z, rv[p].z, acc[rr][p]);
          acc[rr][p] = fmaf(ev.w, rv[p].w, acc[rr][p]);
        }
      }
    }
  }

  // ballot-pack: bit l of word p (for wave row rr) = lane l's sign
  unsigned long long keepA = 0ull, keepB = 0ull;
#pragma unroll
  for (int rr = 0; rr < 16; ++rr)
#pragma unroll
    for (int p = 0; p < 8; ++p) {
      const unsigned long long m = __ballot(acc[rr][p] > 0.0f);
      const int id = rr * 8 + p;                 // 0..127
      if (id < 64) { if (l == id)      keepA = m; }
      else         { if (l == id - 64) keepB = m; }
    }

  // lane l stores word (l&7) of rows w*16 + (l>>3) and +8
  const int rowA = blockRow0 + w * 16 + (l >> 3);
  const int word = bitTile * 8 + (l & 7);
  packed[(size_t)rowA * 16 + word]       = keepA;
  packed[(size_t)(rowA + 8) * 16 + word] = keepB;
}

// ---------------------------------------------------------------------------
// Kernel 2: Hamming (xor + popcount) + cos. EXACT round-3 code (measured
// 88.5 us, VALU 82%). Do not touch.
// Grid (32 n-blocks, 64 m-blocks), block 256 (4 waves).
// Block tile: 64 rows x 256 cols. Thread: 8 rows x 8 cols (2 DS reads/output).
// ---------------------------------------------------------------------------
__global__ __launch_bounds__(256, 3) void lsh_hamming_cos(
    const uint4* __restrict__ up,    // [4096][8]
    const uint4* __restrict__ vp,    // [8192][8]
    const float* __restrict__ pi_in,
    float* __restrict__ out)         // [4096][8192]
{
  __shared__ uint4 u_lds[64 * 8];    // 8 KB, linear
  __shared__ uint4 v_lds[256 * 8];   // 32 KB, swizzled

  const int t  = threadIdx.x;
  const int w  = t >> 6;
  const int l  = t & 63;
  const int n0 = blockIdx.x * 256;
  const int m0 = blockIdx.y * 64;

  // stage U tile (linear, coalesced)
#pragma unroll
  for (int i = 0; i < 2; ++i)
    u_lds[t + i * 256] = up[(size_t)m0 * 8 + t + i * 256];

  // stage V tile (swizzle uint4 slot: w4 -> w4 ^ ((col>>2)&7))
#pragma unroll
  for (int i = 0; i < 8; ++i) {
    const int idx = t + i * 256;
    const int col = idx >> 3;
    const int w4  = idx & 7;
    v_lds[col * 8 + (w4 ^ ((col >> 2) & 7))] = vp[(size_t)n0 * 8 + idx];
  }
  __syncthreads();

  int h[8][8];
#pragma unroll
  for (int r = 0; r < 8; ++r)
#pragma unroll
    for (int j = 0; j < 8; ++j) h[r][j] = 0;

  const int key  = l & 7;
  const int row0 = w * 16 + (l >> 5) * 8;   // thread's first row (block-local)
  const int c0   = (l & 31) * 4;            // thread's first col (block-local)

#pragma unroll
  for (int kk = 0; kk < 8; ++kk) {          // one uint4 (128 bits) per step
    uint4 U[8];
#pragma unroll
    for (int r = 0; r < 8; ++r)
      U[r] = u_lds[(row0 + r) * 8 + kk];    // 2-address broadcast: free
    const int slot = kk ^ key;
#pragma unroll
    for (int half = 0; half < 2; ++half) {
#pragma unroll
      for (int j = 0; j < 4; ++j) {
        const uint4 V = v_lds[(c0 + half * 128 + j) * 8 + slot];
#pragma unroll
        for (int r = 0; r < 8; ++r) {
          int s = h[r][half * 4 + j];
          s += __builtin_popcount(U[r].x ^ V.x);
          s += __builtin_popcount(U[r].y ^ V.y);
          s += __builtin_popcount(U[r].z ^ V.z);
          s += __builtin_popcount(U[r].w ^ V.w);
          h[r][half * 4 + j] = s;
        }
      }
    }
  }

  const float scale = pi_in[0] * (1.0f / (float)NBITS);

#pragma unroll
  for (int r = 0; r < 8; ++r) {
    const size_t row = (size_t)(m0 + row0 + r);
#pragma unroll
    for (int half = 0; half < 2; ++half) {
      float4 o;
      o.x = __cosf(scale * (float)h[r][half * 4 + 0]);
      o.y = __cosf(scale * (float)h[r][half * 4 + 1]);
      o.z = __cosf(scale * (float)h[r][half * 4 + 2]);
      o.w = __cosf(scale * (float)h[r][half * 4 + 3]);
      *(float4*)(out + row * NROWS2 + n0 + c0 + half * 128) = o;
    }
  }
}

// ---------------------------------------------------------------------------
extern "C" void kernel_launch(void* const* d_in, const int* in_sizes, int n_in,
                              void* d_out, int out_size, void* d_ws, size_t ws_size,
                              hipStream_t stream) {
  const float* emb1 = (const float*)d_in[0];   // [4096][128]
  const float* emb2 = (const float*)d_in[1];   // [8192][128]
  const float* r    = (const float*)d_in[2];   // [1024][128]
  const float* pi   = (const float*)d_in[3];   // [1]

  unsigned long long* packed = (unsigned long long*)d_ws;  // [12288][16]

  dim3 g1(192, 2), b1(256);
  lsh_project_pack<<<g1, b1, 0, stream>>>(
      (const float4*)emb1, (const float4*)emb2, (const float4*)r, packed);

  dim3 g2(32, 64), b2(256);
  lsh_hamming_cos<<<g2, b2, 0, stream>>>(
      (const uint4*)packed,
      (const uint4*)(packed + (size_t)NROWS1 * 16),
      pi, (float*)d_out);
}